// Round 14
// baseline (881.897 us; speedup 1.0000x reference)
//
#include <hip/hip_runtime.h>
#include <hip/hip_bf16.h>

#define LRELU_SLOPE 0.2f
#define BN_EPS 1e-5f

typedef __attribute__((ext_vector_type(8))) short short8v;
typedef __attribute__((ext_vector_type(4))) float float4v;

static __device__ __forceinline__ unsigned short f2bf(float f) {
    __hip_bfloat16 b = __float2bfloat16(f);
    return *reinterpret_cast<unsigned short*>(&b);
}
static __device__ __forceinline__ void unpack2(unsigned int u, float& f0, float& f1) {
    f0 = __uint_as_float(u << 16);
    f1 = __uint_as_float(u & 0xffff0000u);
}
static __device__ __forceinline__ float lrelu(float x) {
    return fmaxf(x, LRELU_SLOPE * x);
}

#define CSR_NB 2048  // 8 blocks/CU x 256 CUs; 12 VGPR / 512B LDS -> all co-resident (32 waves/CU)

// software grid barrier: release-fence + monotonic counter + acquire spin.
// Safe because all CSR_NB blocks are co-resident (low VGPR/LDS + launch_bounds).
static __device__ __forceinline__ void gbar(unsigned* bar, unsigned target) {
    __syncthreads();
    if (threadIdx.x == 0) {
        __threadfence();  // release my writes to device scope
        atomicAdd(bar, 1u);
        while (__hip_atomic_load(bar, __ATOMIC_RELAXED, __HIP_MEMORY_SCOPE_AGENT) < target)
            __builtin_amdgcn_s_sleep(8);
        __threadfence();  // acquire: invalidate this CU's L1 before data reads
    }
    __syncthreads();
}

// ---------------- single-kernel CSR build: convert | count | scan | prefix | scatter ----------------
__global__ __launch_bounds__(256, 8) void csr_all_kernel(
    const float* __restrict__ Wl0, const float* __restrict__ Wr0,
    const float* __restrict__ Wl1, const float* __restrict__ Wr1,
    unsigned short* __restrict__ Wt0, unsigned short* __restrict__ Wt1,
    const int* __restrict__ src, const int* __restrict__ dst,
    int* __restrict__ counts, int* __restrict__ cursor,
    int* __restrict__ offs, int* __restrict__ blkSum, int* __restrict__ esrc,
    unsigned* __restrict__ bar,
    int E, int N, int nChunks) {
    const int gtid = blockIdx.x * 256 + threadIdx.x;
    const int gstride = CSR_NB * 256;

    // phase 0: weight convert (no barrier needed: consumed by a later dispatch)
    for (int i = gtid; i < 384 * 128 + 128 * 192; i += gstride) {
        if (i < 384 * 128) {
            int c = i >> 7, k = i & 127;
            float v = (c < 192) ? Wl0[(size_t)k * 192 + c] : Wr0[(size_t)k * 192 + (c - 192)];
            Wt0[i] = f2bf(v);
        } else {
            int i2 = i - 384 * 128;
            int c = i2 / 192, k = i2 % 192;
            float v = (c < 64) ? Wl1[(size_t)k * 64 + c] : Wr1[(size_t)k * 64 + (c - 64)];
            Wt1[i2] = f2bf(v);
        }
    }
    // phase 1: degree count (counts zeroed by host memset)
    for (int e = gtid; e < E; e += gstride) atomicAdd(&counts[dst[e]], 1);
    gbar(bar, CSR_NB);

    // phase 2: per-1024-chunk local exclusive scan (blocks 0..nChunks-1)
    __shared__ int wsum[4];
    __shared__ int baseSh;
    if ((int)blockIdx.x < nChunks) {
        const int lane = threadIdx.x & 63;
        const int wv = threadIdx.x >> 6;
        int i0 = blockIdx.x * 1024 + (int)threadIdx.x * 4;
        int v0 = (i0 + 0 < N) ? counts[i0 + 0] : 0;
        int v1 = (i0 + 1 < N) ? counts[i0 + 1] : 0;
        int v2 = (i0 + 2 < N) ? counts[i0 + 2] : 0;
        int v3 = (i0 + 3 < N) ? counts[i0 + 3] : 0;
        int s4 = v0 + v1 + v2 + v3;
        int s = s4;
        #pragma unroll
        for (int off = 1; off < 64; off <<= 1) {
            int t = __shfl_up(s, off, 64);
            if (lane >= off) s += t;
        }
        if (lane == 63) wsum[wv] = s;
        __syncthreads();
        int wpre = 0;
        for (int w = 0; w < wv; ++w) wpre += wsum[w];
        int excl = wpre + s - s4;
        if (i0 + 0 < N) offs[i0 + 0] = excl;
        excl += v0;
        if (i0 + 1 < N) offs[i0 + 1] = excl;
        excl += v1;
        if (i0 + 2 < N) offs[i0 + 2] = excl;
        excl += v2;
        if (i0 + 3 < N) offs[i0 + 3] = excl;
        if (threadIdx.x == 255) blkSum[blockIdx.x] = wpre + s;
    }
    gbar(bar, 2 * CSR_NB);

    // phase 3: add chunk prefix
    if ((int)blockIdx.x < nChunks) {
        const int b = blockIdx.x;
        if (threadIdx.x < 64) {
            int acc = 0;
            for (int i = threadIdx.x; i < b; i += 64) acc += blkSum[i];
            #pragma unroll
            for (int off = 1; off < 64; off <<= 1) acc += __shfl_xor(acc, off, 64);
            if (threadIdx.x == 0) baseSh = acc;
        }
        __syncthreads();
        const int base = baseSh;
        int i = b * 1024 + (int)threadIdx.x * 4;
        #pragma unroll
        for (int k = 0; k < 4; ++k)
            if (i + k < N) offs[i + k] += base;
        if (b == 0 && threadIdx.x == 0) offs[N] = E;
    }
    gbar(bar, 3 * CSR_NB);

    // phase 4: scatter (cursor zeroed by host memset)
    for (int e = gtid; e < E; e += gstride) {
        int d = dst[e];
        int pos = offs[d] + atomicAdd(&cursor[d], 1);
        esrc[pos] = src[e];
    }
}

// ---------------- MFMA dual GEMM, head-major split output, vectorized epilogue ----------------
// xlB/xrB: [H][N][64] bf16 (H = NCH/64). BN=true: finalize from stats + apply in A staging.
template <int K, int NCH, bool BN>
__global__ __launch_bounds__(256) void mfma_dual_gemm(
    const float* __restrict__ X,
    const unsigned short* __restrict__ Wt,
    const float* __restrict__ bl, const float* __restrict__ br,
    const float* __restrict__ stats, const float* __restrict__ gamma,
    const float* __restrict__ beta, float invN,
    unsigned short* __restrict__ xlB, unsigned short* __restrict__ xrB, int N) {
    constexpr int LDA = 40;
    const int rowBase = blockIdx.x * 128;
    const int colBase = blockIdx.y * 128;

    __shared__ unsigned short SH[16896];  // staging (2x128x40) | epilogue transpose (4x32x132)
    unsigned short* XS = SH;
    unsigned short* WS = SH + 128 * LDA;
    __shared__ float ssA[K], ssB[K];

    const int tid = threadIdx.x;
    const int lane = tid & 63;
    const int wv = tid >> 6;
    const int lrow = lane & 15;
    const int lk = lane >> 4;

    if (BN) {
        for (int c = tid; c < K; c += 256) {
            float mu = stats[c] * invN;
            float var = stats[K + c] * invN - mu * mu;
            float sc = gamma[c] * rsqrtf(var + BN_EPS);
            ssA[c] = sc;
            ssB[c] = beta[c] - mu * sc;
        }
        __syncthreads();
    }

    float4v acc[2][8];
    #pragma unroll
    for (int i = 0; i < 2; ++i)
        #pragma unroll
        for (int j = 0; j < 8; ++j) acc[i][j] = (float4v){0.f, 0.f, 0.f, 0.f};

    for (int k0 = 0; k0 < K; k0 += 32) {
        {
            int r = tid >> 3;
            int kq = (tid & 7) * 4;
            float4 sc0, sc1;
            if (BN) {
                sc0 = *reinterpret_cast<const float4*>(&ssA[k0 + kq]);
                sc1 = *reinterpret_cast<const float4*>(&ssB[k0 + kq]);
            }
            #pragma unroll
            for (int i = 0; i < 4; ++i) {
                int row = r + 32 * i;
                int gr = rowBase + row;
                float4 v = make_float4(0.f, 0.f, 0.f, 0.f);
                if (gr < N) v = *reinterpret_cast<const float4*>(&X[(size_t)gr * K + k0 + kq]);
                if (BN) {
                    v.x = v.x * sc0.x + sc1.x;
                    v.y = v.y * sc0.y + sc1.y;
                    v.z = v.z * sc0.z + sc1.z;
                    v.w = v.w * sc0.w + sc1.w;
                }
                ushort4 u;
                u.x = f2bf(v.x); u.y = f2bf(v.y); u.z = f2bf(v.z); u.w = f2bf(v.w);
                *reinterpret_cast<ushort4*>(&XS[row * LDA + kq]) = u;
            }
        }
        {
            int c = tid >> 2;
            int kq8 = (tid & 3) * 8;
            #pragma unroll
            for (int i = 0; i < 2; ++i) {
                int col = c + 64 * i;
                uint4 w = *reinterpret_cast<const uint4*>(&Wt[(size_t)(colBase + col) * K + k0 + kq8]);
                *reinterpret_cast<uint4*>(&WS[col * LDA + kq8]) = w;
            }
        }
        __syncthreads();
        short8v aF[2], bF[8];
        #pragma unroll
        for (int rb = 0; rb < 2; ++rb)
            aF[rb] = *reinterpret_cast<const short8v*>(&XS[(wv * 32 + rb * 16 + lrow) * LDA + lk * 8]);
        #pragma unroll
        for (int cb = 0; cb < 8; ++cb)
            bF[cb] = *reinterpret_cast<const short8v*>(&WS[(cb * 16 + lrow) * LDA + lk * 8]);
        #pragma unroll
        for (int rb = 0; rb < 2; ++rb)
            #pragma unroll
            for (int cb = 0; cb < 8; ++cb)
                acc[rb][cb] = __builtin_amdgcn_mfma_f32_16x16x32_bf16(aF[rb], bF[cb], acc[rb][cb], 0, 0, 0);
        __syncthreads();  // also fences SH reuse by the epilogue
    }

    // epilogue: bias + per-wave LDS transpose + coalesced uint4 stores
    unsigned short* TR = SH + wv * (32 * 132);
    #pragma unroll
    for (int cb = 0; cb < 8; ++cb) {
        int cgG = colBase + cb * 16 + lrow;
        bool isR = cgG >= NCH;
        int cc = isR ? cgG - NCH : cgG;
        float bv = isR ? br[cc] : bl[cc];
        #pragma unroll
        for (int rb = 0; rb < 2; ++rb) {
            #pragma unroll
            for (int r = 0; r < 4; ++r) {
                int lr = rb * 16 + lk * 4 + r;
                TR[lr * 132 + cb * 16 + lrow] = f2bf(acc[rb][cb][r] + bv);
            }
        }
    }
    #pragma unroll
    for (int it = 0; it < 8; ++it) {
        int idx = it * 64 + lane;
        int lr = idx >> 4;
        int ck = (idx & 15) * 8;
        int grow = rowBase + wv * 32 + lr;
        if (grow < N) {
            uint4 v = *reinterpret_cast<const uint4*>(&TR[lr * 132 + ck]);
            int cgG = colBase + ck;
            bool isR = cgG >= NCH;
            int cc = isR ? cgG - NCH : cgG;
            int hh = cc >> 6;
            int ch = cc & 63;
            unsigned short* dstB = (isR ? xrB : xlB) + (size_t)hh * N * 64 + (size_t)grow * 64 + ch;
            *reinterpret_cast<uint4*>(dstB) = v;
        }
    }
}

// ---------------- GATv2 aggregation layer 0, one head per blockIdx.y (r8/r11 config) ----------------
template <int H>
__global__ __launch_bounds__(256) void gat_agg_head_kernel(
    const unsigned short* __restrict__ xlB,
    const unsigned short* __restrict__ xrB,
    const int* __restrict__ offs, const int* __restrict__ esrc,
    const float* __restrict__ att, const float* __restrict__ bias,
    float* __restrict__ outh, int N) {
    const int h = blockIdx.y;
    const unsigned short* xl_ = xlB + (size_t)h * N * 64;
    const unsigned short* xr_ = xrB + (size_t)h * N * 64;
    const int lane = threadIdx.x & 63;
    const int node = blockIdx.x * 4 + (threadIdx.x >> 6);
    if (node >= N) return;
    const int j = lane >> 3;
    const int cg = (lane & 7) * 8;

    float xr[8], at[8], acc[8];
    float den = 0.f;
    {
        uint4 u = *reinterpret_cast<const uint4*>(&xr_[(size_t)node * 64 + cg]);
        unpack2(u.x, xr[0], xr[1]); unpack2(u.y, xr[2], xr[3]);
        unpack2(u.z, xr[4], xr[5]); unpack2(u.w, xr[6], xr[7]);
        float4 a0 = *reinterpret_cast<const float4*>(&att[h * 64 + cg]);
        float4 a1 = *reinterpret_cast<const float4*>(&att[h * 64 + cg + 4]);
        at[0] = a0.x; at[1] = a0.y; at[2] = a0.z; at[3] = a0.w;
        at[4] = a1.x; at[5] = a1.y; at[6] = a1.z; at[7] = a1.w;
        #pragma unroll
        for (int c = 0; c < 8; ++c) acc[c] = 0.f;
    }

    const int beg = offs[node];
    const int total = offs[node + 1] - beg + 1;  // virtual index 0 = self loop
    uint4 u0, u1;
    {
        int vc = (j < total) ? j : (total - 1);
        int s0 = (vc == 0) ? node : esrc[beg + vc - 1];
        u0 = *reinterpret_cast<const uint4*>(&xl_[(size_t)s0 * 64 + cg]);
        int v1i = j + 8;
        int vc1 = (v1i < total) ? v1i : (total - 1);
        int s1 = (vc1 == 0) ? node : esrc[beg + vc1 - 1];
        u1 = *reinterpret_cast<const uint4*>(&xl_[(size_t)s1 * 64 + cg]);
    }
    for (int t = 0; t < total; t += 8) {
        float xlv[8];
        unpack2(u0.x, xlv[0], xlv[1]); unpack2(u0.y, xlv[2], xlv[3]);
        unpack2(u0.z, xlv[4], xlv[5]); unpack2(u0.w, xlv[6], xlv[7]);
        u0 = u1;
        const int v2 = t + 16 + j;
        if (v2 < total) {
            int s2 = esrc[beg + v2 - 1];
            u1 = *reinterpret_cast<const uint4*>(&xl_[(size_t)s2 * 64 + cg]);
        }
        float s = 0.f;
        #pragma unroll
        for (int c = 0; c < 8; ++c) s += lrelu(xlv[c] + xr[c]) * at[c];
        #pragma unroll
        for (int off = 1; off <= 4; off <<= 1) s += __shfl_xor(s, off, 64);
        const float w = (t + j < total) ? 1.f : 0.f;
        float p = w * __expf(s);
        den += p;
        #pragma unroll
        for (int c = 0; c < 8; ++c) acc[c] += p * xlv[c];
    }

    #pragma unroll
    for (int off = 8; off <= 32; off <<= 1) {
        den += __shfl_xor(den, off, 64);
        #pragma unroll
        for (int c = 0; c < 8; ++c) acc[c] += __shfl_xor(acc[c], off, 64);
    }

    if (j == 0) {
        float inv = 1.f / den;
        float4 b0 = *reinterpret_cast<const float4*>(&bias[h * 64 + cg]);
        float4 b1 = *reinterpret_cast<const float4*>(&bias[h * 64 + cg + 4]);
        float4 o0, o1;
        o0.x = fmaxf(acc[0] * inv + b0.x, 0.f); o0.y = fmaxf(acc[1] * inv + b0.y, 0.f);
        o0.z = fmaxf(acc[2] * inv + b0.z, 0.f); o0.w = fmaxf(acc[3] * inv + b0.w, 0.f);
        o1.x = fmaxf(acc[4] * inv + b1.x, 0.f); o1.y = fmaxf(acc[5] * inv + b1.y, 0.f);
        o1.z = fmaxf(acc[6] * inv + b1.z, 0.f); o1.w = fmaxf(acc[7] * inv + b1.w, 0.f);
        float* orow = &outh[(size_t)node * (H * 64) + h * 64 + cg];
        *reinterpret_cast<float4*>(orow) = o0;
        *reinterpret_cast<float4*>(orow + 4) = o1;
    }
}

// ---------------- GATv2 agg layer 1 + register-accumulated BN stats ----------------
__global__ __launch_bounds__(256) void gat_agg1_bn_kernel(
    const unsigned short* __restrict__ xlB, const unsigned short* __restrict__ xrB,
    const int* __restrict__ offs, const int* __restrict__ esrc,
    const float* __restrict__ att, const float* __restrict__ bias,
    float* __restrict__ outh, float* __restrict__ stats,
    int N, int nGroups) {
    __shared__ float ldsStats[128];
    const int tid = threadIdx.x;
    const int lane = tid & 63;
    const int wv = tid >> 6;
    const int j = lane >> 3;
    const int cg = (lane & 7) * 8;

    float at[8];
    {
        float4 a0 = *reinterpret_cast<const float4*>(&att[cg]);
        float4 a1 = *reinterpret_cast<const float4*>(&att[cg + 4]);
        at[0] = a0.x; at[1] = a0.y; at[2] = a0.z; at[3] = a0.w;
        at[4] = a1.x; at[5] = a1.y; at[6] = a1.z; at[7] = a1.w;
    }
    float sSum[8] = {};
    float sSq[8] = {};

    for (int g = blockIdx.x; g < nGroups; g += gridDim.x) {
        const int node = g * 4 + wv;
        if (node >= N) continue;
        float xr[8], acc[8];
        float den = 0.f;
        {
            uint4 u = *reinterpret_cast<const uint4*>(&xrB[(size_t)node * 64 + cg]);
            unpack2(u.x, xr[0], xr[1]); unpack2(u.y, xr[2], xr[3]);
            unpack2(u.z, xr[4], xr[5]); unpack2(u.w, xr[6], xr[7]);
            #pragma unroll
            for (int c = 0; c < 8; ++c) acc[c] = 0.f;
        }
        const int beg = offs[node];
        const int total = offs[node + 1] - beg + 1;
        uint4 u0, u1;
        {
            int vc = (j < total) ? j : (total - 1);
            int s0 = (vc == 0) ? node : esrc[beg + vc - 1];
            u0 = *reinterpret_cast<const uint4*>(&xlB[(size_t)s0 * 64 + cg]);
            int v1i = j + 8;
            int vc1 = (v1i < total) ? v1i : (total - 1);
            int s1 = (vc1 == 0) ? node : esrc[beg + vc1 - 1];
            u1 = *reinterpret_cast<const uint4*>(&xlB[(size_t)s1 * 64 + cg]);
        }
        for (int t = 0; t < total; t += 8) {
            float xlv[8];
            unpack2(u0.x, xlv[0], xlv[1]); unpack2(u0.y, xlv[2], xlv[3]);
            unpack2(u0.z, xlv[4], xlv[5]); unpack2(u0.w, xlv[6], xlv[7]);
            u0 = u1;
            const int v2 = t + 16 + j;
            if (v2 < total) {
                int s2 = esrc[beg + v2 - 1];
                u1 = *reinterpret_cast<const uint4*>(&xlB[(size_t)s2 * 64 + cg]);
            }
            float s = 0.f;
            #pragma unroll
            for (int c = 0; c < 8; ++c) s += lrelu(xlv[c] + xr[c]) * at[c];
            #pragma unroll
            for (int off = 1; off <= 4; off <<= 1) s += __shfl_xor(s, off, 64);
            const float w = (t + j < total) ? 1.f : 0.f;
            float p = w * __expf(s);
            den += p;
            #pragma unroll
            for (int c = 0; c < 8; ++c) acc[c] += p * xlv[c];
        }
        #pragma unroll
        for (int off = 8; off <= 32; off <<= 1) {
            den += __shfl_xor(den, off, 64);
            #pragma unroll
            for (int c = 0; c < 8; ++c) acc[c] += __shfl_xor(acc[c], off, 64);
        }
        if (j == 0) {
            float inv = 1.f / den;
            float4 b0 = *reinterpret_cast<const float4*>(&bias[cg]);
            float4 b1 = *reinterpret_cast<const float4*>(&bias[cg + 4]);
            float o[8];
            o[0] = fmaxf(acc[0] * inv + b0.x, 0.f); o[1] = fmaxf(acc[1] * inv + b0.y, 0.f);
            o[2] = fmaxf(acc[2] * inv + b0.z, 0.f); o[3] = fmaxf(acc[3] * inv + b0.w, 0.f);
            o[4] = fmaxf(acc[4] * inv + b1.x, 0.f); o[5] = fmaxf(acc[5] * inv + b1.y, 0.f);
            o[6] = fmaxf(acc[6] * inv + b1.z, 0.f); o[7] = fmaxf(acc[7] * inv + b1.w, 0.f);
            *reinterpret_cast<float4*>(&outh[(size_t)node * 64 + cg]) = make_float4(o[0], o[1], o[2], o[3]);
            *reinterpret_cast<float4*>(&outh[(size_t)node * 64 + cg + 4]) = make_float4(o[4], o[5], o[6], o[7]);
            #pragma unroll
            for (int c = 0; c < 8; ++c) {
                sSum[c] += o[c];
                sSq[c] += o[c] * o[c];
            }
        }
    }
    for (int i = tid; i < 128; i += 256) ldsStats[i] = 0.f;
    __syncthreads();
    if (j == 0) {
        #pragma unroll
        for (int c = 0; c < 8; ++c) {
            atomicAdd(&ldsStats[cg + c], sSum[c]);
            atomicAdd(&ldsStats[64 + cg + c], sSq[c]);
        }
    }
    __syncthreads();
    for (int i = tid; i < 128; i += 256) atomicAdd(&stats[i], ldsStats[i]);
}

// ---------------- BatchNorm stats (layer 0) ----------------
template <int CH>
__global__ void bn_stats_kernel(const float* __restrict__ h, float* __restrict__ stats, int N) {
    const int c = threadIdx.x;
    float s = 0.f, q = 0.f;
    for (int r = blockIdx.x; r < N; r += gridDim.x) {
        float v = h[(size_t)r * CH + c];
        s += v;
        q += v * v;
    }
    atomicAdd(&stats[c], s);
    atomicAdd(&stats[CH + c], q);
}

// fused finalize+apply for CH=64
__global__ void bn_finapply64_kernel(float* __restrict__ h, const float* __restrict__ stats,
                                     const float* __restrict__ gamma, const float* __restrict__ beta,
                                     float invN, size_t total4) {
    size_t i = (size_t)blockIdx.x * blockDim.x + threadIdx.x;
    if (i >= total4) return;
    size_t e = i * 4;
    int c = (int)(e & 63);
    float4 v = *reinterpret_cast<float4*>(&h[e]);
    #pragma unroll
    for (int k = 0; k < 4; ++k) {
        float mu = stats[c + k] * invN;
        float var = stats[64 + c + k] * invN - mu * mu;
        float sc = gamma[c + k] * rsqrtf(var + BN_EPS);
        (&v.x)[k] = ((&v.x)[k] - mu) * sc + beta[c + k];
    }
    *reinterpret_cast<float4*>(&h[e]) = v;
}

extern "C" void kernel_launch(void* const* d_in, const int* in_sizes, int n_in,
                              void* d_out, int out_size, void* d_ws, size_t ws_size,
                              hipStream_t stream) {
    const float* x     = (const float*)d_in[0];
    const int*   eidx  = (const int*)d_in[1];
    const float* Wl0   = (const float*)d_in[2];
    const float* bl0   = (const float*)d_in[3];
    const float* Wr0   = (const float*)d_in[4];
    const float* br0   = (const float*)d_in[5];
    const float* att0  = (const float*)d_in[6];
    const float* bias0 = (const float*)d_in[7];
    const float* g0    = (const float*)d_in[8];
    const float* be0   = (const float*)d_in[9];
    const float* Wl1   = (const float*)d_in[10];
    const float* bl1   = (const float*)d_in[11];
    const float* Wr1   = (const float*)d_in[12];
    const float* br1   = (const float*)d_in[13];
    const float* att1  = (const float*)d_in[14];
    const float* bias1 = (const float*)d_in[15];
    const float* g1    = (const float*)d_in[16];
    const float* be1   = (const float*)d_in[17];

    const int N = in_sizes[0] / 128;
    const int E = in_sizes[1] / 2;
    const int* srcIdx = eidx;
    const int* dstIdx = eidx + E;
    const int nChunks = (N + 1023) >> 10;
    const int nGroups = (N + 3) / 4;
    const float invN = 1.f / (float)N;

    char* base = (char*)d_ws;
    auto alloc = [&](size_t bytes) {
        char* p = base;
        base += (bytes + 255) & ~(size_t)255;
        return p;
    };
    unsigned short* projL = (unsigned short*)alloc((size_t)3 * N * 64 * 2);  // [H][N][64]
    unsigned short* projR = (unsigned short*)alloc((size_t)3 * N * 64 * 2);
    float* h0    = (float*)alloc((size_t)N * 192 * 4);
    int*   offs  = (int*)alloc((size_t)(N + 1) * 4);
    int*   esrc  = (int*)alloc((size_t)E * 4);
    int*   blkSum= (int*)alloc((size_t)nChunks * 4);
    unsigned short* Wt0 = (unsigned short*)alloc((size_t)384 * 128 * 2);
    unsigned short* Wt1 = (unsigned short*)alloc((size_t)128 * 192 * 2);
    // contiguous zero region: bar | counts | cursor | stats0 | stats1
    char* zeroBeg = base;
    unsigned* bar = (unsigned*)alloc(256);
    int*   counts = (int*)alloc((size_t)N * 4);
    int*   cursor = (int*)alloc((size_t)N * 4);
    float* stats0 = (float*)alloc(384 * 4);
    float* stats1 = (float*)alloc(128 * 4);
    size_t zeroBytes = (size_t)(base - zeroBeg);

    // ---- 1. zero region ----
    hipMemsetAsync(zeroBeg, 0, zeroBytes, stream);

    // ---- 2. single-kernel CSR build (convert | count | scan | prefix | scatter) ----
    csr_all_kernel<<<CSR_NB, 256, 0, stream>>>(Wl0, Wr0, Wl1, Wr1, Wt0, Wt1,
                                               srcIdx, dstIdx, counts, cursor,
                                               offs, blkSum, esrc, bar, E, N, nChunks);

    // ---- 3. layer 0 GEMM: 128 -> 3x64 | 3x64 ----
    {
        dim3 grid((N + 127) / 128, 3);
        mfma_dual_gemm<128, 192, false><<<grid, 256, 0, stream>>>(
            x, Wt0, bl0, br0, nullptr, nullptr, nullptr, 0.f, projL, projR, N);
    }

    // ---- 4. layer 0 aggregation (per-head) ----
    {
        dim3 grid(nGroups, 3);
        gat_agg_head_kernel<3><<<grid, 256, 0, stream>>>(projL, projR, offs, esrc, att0, bias0, h0, N);
    }

    // ---- 5. layer 0 BN stats ----
    bn_stats_kernel<192><<<256, 192, 0, stream>>>(h0, stats0, N);

    // ---- 6. layer 1 GEMM (BN finalize+apply fused into A staging) ----
    {
        dim3 grid((N + 127) / 128, 1);
        mfma_dual_gemm<192, 64, true><<<grid, 256, 0, stream>>>(
            h0, Wt1, bl1, br1, stats0, g0, be0, invN, projL, projR, N);
    }

    // ---- 7. layer 1 aggregation + register-fused BN stats ----
    float* out = (float*)d_out;
    {
        int blocks = nGroups < 1024 ? nGroups : 1024;
        gat_agg1_bn_kernel<<<blocks, 256, 0, stream>>>(projL, projR, offs, esrc, att1, bias1,
                                                       out, stats1, N, nGroups);
    }

    // ---- 8. layer 1 BN finalize + apply ----
    {
        size_t tot4 = (size_t)N * 16;
        bn_finapply64_kernel<<<(unsigned)((tot4 + 255) / 256), 256, 0, stream>>>(out, stats1, g1, be1, invN, tot4);
    }
}

// Round 15
// 340.275 us; speedup vs baseline: 2.5917x; 2.5917x over previous
//
#include <hip/hip_runtime.h>
#include <hip/hip_bf16.h>

#define LRELU_SLOPE 0.2f
#define BN_EPS 1e-5f

typedef __attribute__((ext_vector_type(8))) short short8v;
typedef __attribute__((ext_vector_type(4))) float float4v;

static __device__ __forceinline__ unsigned short f2bf(float f) {
    __hip_bfloat16 b = __float2bfloat16(f);
    return *reinterpret_cast<unsigned short*>(&b);
}
static __device__ __forceinline__ void unpack2(unsigned int u, float& f0, float& f1) {
    f0 = __uint_as_float(u << 16);
    f1 = __uint_as_float(u & 0xffff0000u);
}
static __device__ __forceinline__ float lrelu(float x) {
    return fmaxf(x, LRELU_SLOPE * x);
}

// ---------------- fused: weight pre-convert + dst-degree count ----------------
__global__ void convcount_kernel(const float* __restrict__ Wl0, const float* __restrict__ Wr0,
                                 const float* __restrict__ Wl1, const float* __restrict__ Wr1,
                                 unsigned short* __restrict__ Wt0, unsigned short* __restrict__ Wt1,
                                 const int* __restrict__ dst, int* __restrict__ counts, int E) {
    int idx = blockIdx.x * blockDim.x + threadIdx.x;
    if (idx < 384 * 128) {
        int c = idx >> 7, k = idx & 127;
        float v = (c < 192) ? Wl0[(size_t)k * 192 + c] : Wr0[(size_t)k * 192 + (c - 192)];
        Wt0[idx] = f2bf(v);
    } else if (idx < 384 * 128 + 128 * 192) {
        int i2 = idx - 384 * 128;
        int c = i2 / 192, k = i2 % 192;
        float v = (c < 64) ? Wl1[(size_t)k * 64 + c] : Wr1[(size_t)k * 64 + (c - 64)];
        Wt1[i2] = f2bf(v);
    }
    if (idx < E) atomicAdd(&counts[dst[idx]], 1);
}

// ---------------- CSR build (by dst) ----------------
__global__ void scanA_kernel(const int* __restrict__ counts, int* __restrict__ offs,
                             int* __restrict__ blkSum, int n) {
    __shared__ int wsum[4];
    const int lane = threadIdx.x & 63;
    const int wv = threadIdx.x >> 6;
    int i0 = blockIdx.x * 1024 + (int)threadIdx.x * 4;
    int v0 = (i0 + 0 < n) ? counts[i0 + 0] : 0;
    int v1 = (i0 + 1 < n) ? counts[i0 + 1] : 0;
    int v2 = (i0 + 2 < n) ? counts[i0 + 2] : 0;
    int v3 = (i0 + 3 < n) ? counts[i0 + 3] : 0;
    int s4 = v0 + v1 + v2 + v3;
    int s = s4;
    #pragma unroll
    for (int off = 1; off < 64; off <<= 1) {
        int t = __shfl_up(s, off, 64);
        if (lane >= off) s += t;
    }
    if (lane == 63) wsum[wv] = s;
    __syncthreads();
    int wpre = 0;
    for (int w = 0; w < wv; ++w) wpre += wsum[w];
    int excl = wpre + s - s4;
    if (i0 + 0 < n) offs[i0 + 0] = excl;
    excl += v0;
    if (i0 + 1 < n) offs[i0 + 1] = excl;
    excl += v1;
    if (i0 + 2 < n) offs[i0 + 2] = excl;
    excl += v2;
    if (i0 + 3 < n) offs[i0 + 3] = excl;
    if (threadIdx.x == 255) blkSum[blockIdx.x] = wpre + s;
}

__global__ void scanC_kernel(int* __restrict__ offs, const int* __restrict__ blkSum, int n, int E) {
    __shared__ int baseSh;
    const int b = blockIdx.x;
    if (threadIdx.x < 64) {
        int acc = 0;
        for (int i = threadIdx.x; i < b; i += 64) acc += blkSum[i];
        #pragma unroll
        for (int off = 1; off < 64; off <<= 1) acc += __shfl_xor(acc, off, 64);
        if (threadIdx.x == 0) baseSh = acc;
    }
    __syncthreads();
    const int base = baseSh;
    int i = b * 1024 + (int)threadIdx.x * 4;
    if (i + 3 < n) {
        int4 v = *reinterpret_cast<int4*>(&offs[i]);
        v.x += base; v.y += base; v.z += base; v.w += base;
        *reinterpret_cast<int4*>(&offs[i]) = v;
    } else {
        #pragma unroll
        for (int k = 0; k < 4; ++k)
            if (i + k < n) offs[i + k] += base;
    }
    if (b == 0 && threadIdx.x == 0) offs[n] = E;
}

__global__ void scatter_kernel(const int* __restrict__ src, const int* __restrict__ dst,
                               const int* __restrict__ offs, int* __restrict__ cursor,
                               int* __restrict__ esrc, int E) {
    int e = blockIdx.x * blockDim.x + threadIdx.x;
    if (e < E) {
        int d = dst[e];
        int pos = offs[d] + atomicAdd(&cursor[d], 1);
        esrc[pos] = src[e];
    }
}

// ---------------- MFMA dual GEMM, head-major split output, vectorized epilogue ----------------
// xlB/xrB: [H][N][64] bf16 (H = NCH/64). BN=true: finalize from stats + apply in A staging.
template <int K, int NCH, bool BN>
__global__ __launch_bounds__(256) void mfma_dual_gemm(
    const float* __restrict__ X,
    const unsigned short* __restrict__ Wt,
    const float* __restrict__ bl, const float* __restrict__ br,
    const float* __restrict__ stats, const float* __restrict__ gamma,
    const float* __restrict__ beta, float invN,
    unsigned short* __restrict__ xlB, unsigned short* __restrict__ xrB, int N) {
    constexpr int LDA = 40;
    const int rowBase = blockIdx.x * 128;
    const int colBase = blockIdx.y * 128;

    __shared__ unsigned short SH[16896];  // staging (2x128x40) | epilogue transpose (4x32x132)
    unsigned short* XS = SH;
    unsigned short* WS = SH + 128 * LDA;
    __shared__ float ssA[K], ssB[K];

    const int tid = threadIdx.x;
    const int lane = tid & 63;
    const int wv = tid >> 6;
    const int lrow = lane & 15;
    const int lk = lane >> 4;

    if (BN) {
        for (int c = tid; c < K; c += 256) {
            float mu = stats[c] * invN;
            float var = stats[K + c] * invN - mu * mu;
            float sc = gamma[c] * rsqrtf(var + BN_EPS);
            ssA[c] = sc;
            ssB[c] = beta[c] - mu * sc;
        }
        __syncthreads();
    }

    float4v acc[2][8];
    #pragma unroll
    for (int i = 0; i < 2; ++i)
        #pragma unroll
        for (int j = 0; j < 8; ++j) acc[i][j] = (float4v){0.f, 0.f, 0.f, 0.f};

    for (int k0 = 0; k0 < K; k0 += 32) {
        {
            int r = tid >> 3;
            int kq = (tid & 7) * 4;
            float4 sc0, sc1;
            if (BN) {
                sc0 = *reinterpret_cast<const float4*>(&ssA[k0 + kq]);
                sc1 = *reinterpret_cast<const float4*>(&ssB[k0 + kq]);
            }
            #pragma unroll
            for (int i = 0; i < 4; ++i) {
                int row = r + 32 * i;
                int gr = rowBase + row;
                float4 v = make_float4(0.f, 0.f, 0.f, 0.f);
                if (gr < N) v = *reinterpret_cast<const float4*>(&X[(size_t)gr * K + k0 + kq]);
                if (BN) {
                    v.x = v.x * sc0.x + sc1.x;
                    v.y = v.y * sc0.y + sc1.y;
                    v.z = v.z * sc0.z + sc1.z;
                    v.w = v.w * sc0.w + sc1.w;
                }
                ushort4 u;
                u.x = f2bf(v.x); u.y = f2bf(v.y); u.z = f2bf(v.z); u.w = f2bf(v.w);
                *reinterpret_cast<ushort4*>(&XS[row * LDA + kq]) = u;
            }
        }
        {
            int c = tid >> 2;
            int kq8 = (tid & 3) * 8;
            #pragma unroll
            for (int i = 0; i < 2; ++i) {
                int col = c + 64 * i;
                uint4 w = *reinterpret_cast<const uint4*>(&Wt[(size_t)(colBase + col) * K + k0 + kq8]);
                *reinterpret_cast<uint4*>(&WS[col * LDA + kq8]) = w;
            }
        }
        __syncthreads();
        short8v aF[2], bF[8];
        #pragma unroll
        for (int rb = 0; rb < 2; ++rb)
            aF[rb] = *reinterpret_cast<const short8v*>(&XS[(wv * 32 + rb * 16 + lrow) * LDA + lk * 8]);
        #pragma unroll
        for (int cb = 0; cb < 8; ++cb)
            bF[cb] = *reinterpret_cast<const short8v*>(&WS[(cb * 16 + lrow) * LDA + lk * 8]);
        #pragma unroll
        for (int rb = 0; rb < 2; ++rb)
            #pragma unroll
            for (int cb = 0; cb < 8; ++cb)
                acc[rb][cb] = __builtin_amdgcn_mfma_f32_16x16x32_bf16(aF[rb], bF[cb], acc[rb][cb], 0, 0, 0);
        __syncthreads();  // also fences SH reuse by the epilogue
    }

    // epilogue: bias + per-wave LDS transpose + coalesced uint4 stores
    unsigned short* TR = SH + wv * (32 * 132);
    #pragma unroll
    for (int cb = 0; cb < 8; ++cb) {
        int cgG = colBase + cb * 16 + lrow;
        bool isR = cgG >= NCH;
        int cc = isR ? cgG - NCH : cgG;
        float bv = isR ? br[cc] : bl[cc];
        #pragma unroll
        for (int rb = 0; rb < 2; ++rb) {
            #pragma unroll
            for (int r = 0; r < 4; ++r) {
                int lr = rb * 16 + lk * 4 + r;
                TR[lr * 132 + cb * 16 + lrow] = f2bf(acc[rb][cb][r] + bv);
            }
        }
    }
    #pragma unroll
    for (int it = 0; it < 8; ++it) {
        int idx = it * 64 + lane;
        int lr = idx >> 4;
        int ck = (idx & 15) * 8;
        int grow = rowBase + wv * 32 + lr;
        if (grow < N) {
            uint4 v = *reinterpret_cast<const uint4*>(&TR[lr * 132 + ck]);
            int cgG = colBase + ck;
            bool isR = cgG >= NCH;
            int cc = isR ? cgG - NCH : cgG;
            int hh = cc >> 6;
            int ch = cc & 63;
            unsigned short* dstB = (isR ? xrB : xlB) + (size_t)hh * N * 64 + (size_t)grow * 64 + ch;
            *reinterpret_cast<uint4*>(dstB) = v;
        }
    }
}

// ---------------- GATv2 aggregation layer 0, one head per blockIdx.y (r8/r11 config) ----------------
template <int H>
__global__ __launch_bounds__(256) void gat_agg_head_kernel(
    const unsigned short* __restrict__ xlB,
    const unsigned short* __restrict__ xrB,
    const int* __restrict__ offs, const int* __restrict__ esrc,
    const float* __restrict__ att, const float* __restrict__ bias,
    float* __restrict__ outh, int N) {
    const int h = blockIdx.y;
    const unsigned short* xl_ = xlB + (size_t)h * N * 64;
    const unsigned short* xr_ = xrB + (size_t)h * N * 64;
    const int lane = threadIdx.x & 63;
    const int node = blockIdx.x * 4 + (threadIdx.x >> 6);
    if (node >= N) return;
    const int j = lane >> 3;
    const int cg = (lane & 7) * 8;

    float xr[8], at[8], acc[8];
    float den = 0.f;
    {
        uint4 u = *reinterpret_cast<const uint4*>(&xr_[(size_t)node * 64 + cg]);
        unpack2(u.x, xr[0], xr[1]); unpack2(u.y, xr[2], xr[3]);
        unpack2(u.z, xr[4], xr[5]); unpack2(u.w, xr[6], xr[7]);
        float4 a0 = *reinterpret_cast<const float4*>(&att[h * 64 + cg]);
        float4 a1 = *reinterpret_cast<const float4*>(&att[h * 64 + cg + 4]);
        at[0] = a0.x; at[1] = a0.y; at[2] = a0.z; at[3] = a0.w;
        at[4] = a1.x; at[5] = a1.y; at[6] = a1.z; at[7] = a1.w;
        #pragma unroll
        for (int c = 0; c < 8; ++c) acc[c] = 0.f;
    }

    const int beg = offs[node];
    const int total = offs[node + 1] - beg + 1;  // virtual index 0 = self loop
    uint4 u0, u1;
    {
        int vc = (j < total) ? j : (total - 1);
        int s0 = (vc == 0) ? node : esrc[beg + vc - 1];
        u0 = *reinterpret_cast<const uint4*>(&xl_[(size_t)s0 * 64 + cg]);
        int v1i = j + 8;
        int vc1 = (v1i < total) ? v1i : (total - 1);
        int s1 = (vc1 == 0) ? node : esrc[beg + vc1 - 1];
        u1 = *reinterpret_cast<const uint4*>(&xl_[(size_t)s1 * 64 + cg]);
    }
    for (int t = 0; t < total; t += 8) {
        float xlv[8];
        unpack2(u0.x, xlv[0], xlv[1]); unpack2(u0.y, xlv[2], xlv[3]);
        unpack2(u0.z, xlv[4], xlv[5]); unpack2(u0.w, xlv[6], xlv[7]);
        u0 = u1;
        const int v2 = t + 16 + j;
        if (v2 < total) {
            int s2 = esrc[beg + v2 - 1];
            u1 = *reinterpret_cast<const uint4*>(&xl_[(size_t)s2 * 64 + cg]);
        }
        float s = 0.f;
        #pragma unroll
        for (int c = 0; c < 8; ++c) s += lrelu(xlv[c] + xr[c]) * at[c];
        #pragma unroll
        for (int off = 1; off <= 4; off <<= 1) s += __shfl_xor(s, off, 64);
        const float w = (t + j < total) ? 1.f : 0.f;
        float p = w * __expf(s);
        den += p;
        #pragma unroll
        for (int c = 0; c < 8; ++c) acc[c] += p * xlv[c];
    }

    #pragma unroll
    for (int off = 8; off <= 32; off <<= 1) {
        den += __shfl_xor(den, off, 64);
        #pragma unroll
        for (int c = 0; c < 8; ++c) acc[c] += __shfl_xor(acc[c], off, 64);
    }

    if (j == 0) {
        float inv = 1.f / den;
        float4 b0 = *reinterpret_cast<const float4*>(&bias[h * 64 + cg]);
        float4 b1 = *reinterpret_cast<const float4*>(&bias[h * 64 + cg + 4]);
        float4 o0, o1;
        o0.x = fmaxf(acc[0] * inv + b0.x, 0.f); o0.y = fmaxf(acc[1] * inv + b0.y, 0.f);
        o0.z = fmaxf(acc[2] * inv + b0.z, 0.f); o0.w = fmaxf(acc[3] * inv + b0.w, 0.f);
        o1.x = fmaxf(acc[4] * inv + b1.x, 0.f); o1.y = fmaxf(acc[5] * inv + b1.y, 0.f);
        o1.z = fmaxf(acc[6] * inv + b1.z, 0.f); o1.w = fmaxf(acc[7] * inv + b1.w, 0.f);
        float* orow = &outh[(size_t)node * (H * 64) + h * 64 + cg];
        *reinterpret_cast<float4*>(orow) = o0;
        *reinterpret_cast<float4*>(orow + 4) = o1;
    }
}

// ---------------- GATv2 agg layer 1 + register-accumulated BN stats ----------------
__global__ __launch_bounds__(256) void gat_agg1_bn_kernel(
    const unsigned short* __restrict__ xlB, const unsigned short* __restrict__ xrB,
    const int* __restrict__ offs, const int* __restrict__ esrc,
    const float* __restrict__ att, const float* __restrict__ bias,
    float* __restrict__ outh, float* __restrict__ stats,
    int N, int nGroups) {
    __shared__ float ldsStats[128];
    const int tid = threadIdx.x;
    const int lane = tid & 63;
    const int wv = tid >> 6;
    const int j = lane >> 3;
    const int cg = (lane & 7) * 8;

    float at[8];
    {
        float4 a0 = *reinterpret_cast<const float4*>(&att[cg]);
        float4 a1 = *reinterpret_cast<const float4*>(&att[cg + 4]);
        at[0] = a0.x; at[1] = a0.y; at[2] = a0.z; at[3] = a0.w;
        at[4] = a1.x; at[5] = a1.y; at[6] = a1.z; at[7] = a1.w;
    }
    float sSum[8] = {};
    float sSq[8] = {};

    for (int g = blockIdx.x; g < nGroups; g += gridDim.x) {
        const int node = g * 4 + wv;
        if (node >= N) continue;
        float xr[8], acc[8];
        float den = 0.f;
        {
            uint4 u = *reinterpret_cast<const uint4*>(&xrB[(size_t)node * 64 + cg]);
            unpack2(u.x, xr[0], xr[1]); unpack2(u.y, xr[2], xr[3]);
            unpack2(u.z, xr[4], xr[5]); unpack2(u.w, xr[6], xr[7]);
            #pragma unroll
            for (int c = 0; c < 8; ++c) acc[c] = 0.f;
        }
        const int beg = offs[node];
        const int total = offs[node + 1] - beg + 1;
        uint4 u0, u1;
        {
            int vc = (j < total) ? j : (total - 1);
            int s0 = (vc == 0) ? node : esrc[beg + vc - 1];
            u0 = *reinterpret_cast<const uint4*>(&xlB[(size_t)s0 * 64 + cg]);
            int v1i = j + 8;
            int vc1 = (v1i < total) ? v1i : (total - 1);
            int s1 = (vc1 == 0) ? node : esrc[beg + vc1 - 1];
            u1 = *reinterpret_cast<const uint4*>(&xlB[(size_t)s1 * 64 + cg]);
        }
        for (int t = 0; t < total; t += 8) {
            float xlv[8];
            unpack2(u0.x, xlv[0], xlv[1]); unpack2(u0.y, xlv[2], xlv[3]);
            unpack2(u0.z, xlv[4], xlv[5]); unpack2(u0.w, xlv[6], xlv[7]);
            u0 = u1;
            const int v2 = t + 16 + j;
            if (v2 < total) {
                int s2 = esrc[beg + v2 - 1];
                u1 = *reinterpret_cast<const uint4*>(&xlB[(size_t)s2 * 64 + cg]);
            }
            float s = 0.f;
            #pragma unroll
            for (int c = 0; c < 8; ++c) s += lrelu(xlv[c] + xr[c]) * at[c];
            #pragma unroll
            for (int off = 1; off <= 4; off <<= 1) s += __shfl_xor(s, off, 64);
            const float w = (t + j < total) ? 1.f : 0.f;
            float p = w * __expf(s);
            den += p;
            #pragma unroll
            for (int c = 0; c < 8; ++c) acc[c] += p * xlv[c];
        }
        #pragma unroll
        for (int off = 8; off <= 32; off <<= 1) {
            den += __shfl_xor(den, off, 64);
            #pragma unroll
            for (int c = 0; c < 8; ++c) acc[c] += __shfl_xor(acc[c], off, 64);
        }
        if (j == 0) {
            float inv = 1.f / den;
            float4 b0 = *reinterpret_cast<const float4*>(&bias[cg]);
            float4 b1 = *reinterpret_cast<const float4*>(&bias[cg + 4]);
            float o[8];
            o[0] = fmaxf(acc[0] * inv + b0.x, 0.f); o[1] = fmaxf(acc[1] * inv + b0.y, 0.f);
            o[2] = fmaxf(acc[2] * inv + b0.z, 0.f); o[3] = fmaxf(acc[3] * inv + b0.w, 0.f);
            o[4] = fmaxf(acc[4] * inv + b1.x, 0.f); o[5] = fmaxf(acc[5] * inv + b1.y, 0.f);
            o[6] = fmaxf(acc[6] * inv + b1.z, 0.f); o[7] = fmaxf(acc[7] * inv + b1.w, 0.f);
            *reinterpret_cast<float4*>(&outh[(size_t)node * 64 + cg]) = make_float4(o[0], o[1], o[2], o[3]);
            *reinterpret_cast<float4*>(&outh[(size_t)node * 64 + cg + 4]) = make_float4(o[4], o[5], o[6], o[7]);
            #pragma unroll
            for (int c = 0; c < 8; ++c) {
                sSum[c] += o[c];
                sSq[c] += o[c] * o[c];
            }
        }
    }
    for (int i = tid; i < 128; i += 256) ldsStats[i] = 0.f;
    __syncthreads();
    if (j == 0) {
        #pragma unroll
        for (int c = 0; c < 8; ++c) {
            atomicAdd(&ldsStats[cg + c], sSum[c]);
            atomicAdd(&ldsStats[64 + cg + c], sSq[c]);
        }
    }
    __syncthreads();
    for (int i = tid; i < 128; i += 256) atomicAdd(&stats[i], ldsStats[i]);
}

// ---------------- BatchNorm stats (layer 0) ----------------
template <int CH>
__global__ void bn_stats_kernel(const float* __restrict__ h, float* __restrict__ stats, int N) {
    const int c = threadIdx.x;
    float s = 0.f, q = 0.f;
    for (int r = blockIdx.x; r < N; r += gridDim.x) {
        float v = h[(size_t)r * CH + c];
        s += v;
        q += v * v;
    }
    atomicAdd(&stats[c], s);
    atomicAdd(&stats[CH + c], q);
}

// fused finalize+apply for CH=64
__global__ void bn_finapply64_kernel(float* __restrict__ h, const float* __restrict__ stats,
                                     const float* __restrict__ gamma, const float* __restrict__ beta,
                                     float invN, size_t total4) {
    size_t i = (size_t)blockIdx.x * blockDim.x + threadIdx.x;
    if (i >= total4) return;
    size_t e = i * 4;
    int c = (int)(e & 63);
    float4 v = *reinterpret_cast<float4*>(&h[e]);
    #pragma unroll
    for (int k = 0; k < 4; ++k) {
        float mu = stats[c + k] * invN;
        float var = stats[64 + c + k] * invN - mu * mu;
        float sc = gamma[c + k] * rsqrtf(var + BN_EPS);
        (&v.x)[k] = ((&v.x)[k] - mu) * sc + beta[c + k];
    }
    *reinterpret_cast<float4*>(&h[e]) = v;
}

extern "C" void kernel_launch(void* const* d_in, const int* in_sizes, int n_in,
                              void* d_out, int out_size, void* d_ws, size_t ws_size,
                              hipStream_t stream) {
    const float* x     = (const float*)d_in[0];
    const int*   eidx  = (const int*)d_in[1];
    const float* Wl0   = (const float*)d_in[2];
    const float* bl0   = (const float*)d_in[3];
    const float* Wr0   = (const float*)d_in[4];
    const float* br0   = (const float*)d_in[5];
    const float* att0  = (const float*)d_in[6];
    const float* bias0 = (const float*)d_in[7];
    const float* g0    = (const float*)d_in[8];
    const float* be0   = (const float*)d_in[9];
    const float* Wl1   = (const float*)d_in[10];
    const float* bl1   = (const float*)d_in[11];
    const float* Wr1   = (const float*)d_in[12];
    const float* br1   = (const float*)d_in[13];
    const float* att1  = (const float*)d_in[14];
    const float* bias1 = (const float*)d_in[15];
    const float* g1    = (const float*)d_in[16];
    const float* be1   = (const float*)d_in[17];

    const int N = in_sizes[0] / 128;
    const int E = in_sizes[1] / 2;
    const int* srcIdx = eidx;
    const int* dstIdx = eidx + E;
    const int nChunks = (N + 1023) >> 10;
    const int nGroups = (N + 3) / 4;
    const float invN = 1.f / (float)N;

    char* base = (char*)d_ws;
    auto alloc = [&](size_t bytes) {
        char* p = base;
        base += (bytes + 255) & ~(size_t)255;
        return p;
    };
    unsigned short* projL = (unsigned short*)alloc((size_t)3 * N * 64 * 2);  // [H][N][64]
    unsigned short* projR = (unsigned short*)alloc((size_t)3 * N * 64 * 2);
    float* h0    = (float*)alloc((size_t)N * 192 * 4);
    int*   offs  = (int*)alloc((size_t)(N + 1) * 4);
    int*   esrc  = (int*)alloc((size_t)E * 4);
    int*   blkSum= (int*)alloc((size_t)nChunks * 4);
    unsigned short* Wt0 = (unsigned short*)alloc((size_t)384 * 128 * 2);
    unsigned short* Wt1 = (unsigned short*)alloc((size_t)128 * 192 * 2);
    // contiguous zero region: counts | cursor | stats0 | stats1
    char* zeroBeg = base;
    int*   counts = (int*)alloc((size_t)N * 4);
    int*   cursor = (int*)alloc((size_t)N * 4);
    float* stats0 = (float*)alloc(384 * 4);
    float* stats1 = (float*)alloc(128 * 4);
    size_t zeroBytes = (size_t)(base - zeroBeg);

    hipMemsetAsync(zeroBeg, 0, zeroBytes, stream);

    // ---- CSR build: convert+count | scan | prefix | scatter ----
    {
        int work = E > (384 * 128 + 128 * 192) ? E : (384 * 128 + 128 * 192);
        convcount_kernel<<<(work + 255) / 256, 256, 0, stream>>>(Wl0, Wr0, Wl1, Wr1, Wt0, Wt1, dstIdx, counts, E);
    }
    scanA_kernel<<<nChunks, 256, 0, stream>>>(counts, offs, blkSum, N);
    scanC_kernel<<<nChunks, 256, 0, stream>>>(offs, blkSum, N, E);
    scatter_kernel<<<(E + 255) / 256, 256, 0, stream>>>(srcIdx, dstIdx, offs, cursor, esrc, E);

    // ---- layer 0 GEMM: 128 -> 3x64 | 3x64 ----
    {
        dim3 grid((N + 127) / 128, 3);
        mfma_dual_gemm<128, 192, false><<<grid, 256, 0, stream>>>(
            x, Wt0, bl0, br0, nullptr, nullptr, nullptr, 0.f, projL, projR, N);
    }

    // ---- layer 0 aggregation (per-head) ----
    {
        dim3 grid(nGroups, 3);
        gat_agg_head_kernel<3><<<grid, 256, 0, stream>>>(projL, projR, offs, esrc, att0, bias0, h0, N);
    }

    // ---- layer 0 BN stats ----
    bn_stats_kernel<192><<<256, 192, 0, stream>>>(h0, stats0, N);

    // ---- layer 1 GEMM (BN finalize+apply fused into A staging) ----
    {
        dim3 grid((N + 127) / 128, 1);
        mfma_dual_gemm<192, 64, true><<<grid, 256, 0, stream>>>(
            h0, Wt1, bl1, br1, stats0, g0, be0, invN, projL, projR, N);
    }

    // ---- layer 1 aggregation + register-fused BN stats ----
    float* out = (float*)d_out;
    {
        int blocks = nGroups < 1024 ? nGroups : 1024;
        gat_agg1_bn_kernel<<<blocks, 256, 0, stream>>>(projL, projR, offs, esrc, att1, bias1,
                                                       out, stats1, N, nGroups);
    }

    // ---- layer 1 BN finalize + apply ----
    {
        size_t tot4 = (size_t)N * 16;
        bn_finapply64_kernel<<<(unsigned)((tot4 + 255) / 256), 256, 0, stream>>>(out, stats1, g1, be1, invN, tot4);
    }
}